// Round 10
// baseline (98.239 us; speedup 1.0000x reference)
//
#include <hip/hip_runtime.h>
#include <hip/hip_bf16.h>

using bf16x8 = __attribute__((ext_vector_type(8))) short;
using bf16x4 = __attribute__((ext_vector_type(4))) short;
using f32x4  = __attribute__((ext_vector_type(4))) float;

namespace {
constexpr int nB = 128, nS = 300, nC = 64, nH = 768, nM = 300;
constexpr int MT  = 160;            // m-tile per block (2 blocks per b)
constexpr int KC  = 64;             // k chunk (2 substeps of 32, 1 barrier)
constexpr int NKC = nH / KC;        // 12
// LDS (bytes). K-loop: two staging buffers [0, 139264).
// Post-K-loop overlays: GTS [0,49152); after PV: W2R [0,44032).
// RED1/RED2 past the buffers.
constexpr int BUFSZ    = 69632;     // ctx 40960 + pos 20480 + resp 8192
constexpr int STG_CTX  = 0;         // [320 s][128 B] bf16 chunk, XOR-swizzled
constexpr int STG_POS  = 40960;     // [160 m][128 B]
constexpr int STG_RESP = 61440;     // [64 c][128 B]
constexpr int GTSOF    = 0;         // [64 c][768 B] bf16, XOR (c&15)<<3
constexpr int W2R      = 0;         // [64 c][172 f32] (post-PV only)
constexpr int RED1     = 139264;    // 2560 B (softmax max / final fred 2048)
constexpr int RED2     = 141824;    // 2560 B (softmax sum)
constexpr int LDSB     = 144384;
}

// fp32 -> bf16 RNE manual bit-twiddle (proven rounds 2-8)
__device__ __forceinline__ unsigned short bf16rne(float f) {
    unsigned u = __float_as_uint(f);
    return (unsigned short)((u + 0x7FFFu + ((u >> 16) & 1u)) >> 16);
}
__device__ __forceinline__ unsigned pack2(float a, float b) {
    return (unsigned)bf16rne(a) | ((unsigned)bf16rne(b) << 16);
}
__device__ __forceinline__ uint2 cvt4(float4 v) {
    return make_uint2(pack2(v.x, v.y), pack2(v.z, v.w));
}
// 128B-row staging swizzle: XOR row bits into byte bits [6:4] so a 16-lane
// fragment read (rows r..r+15, fixed 16B col) spreads over 8 bank-quads
// (2 lanes/quad = conflict-free, m136). Bijective within each row.
__device__ __forceinline__ int swz(int row, int bcol) {
    return row * 128 + (bcol ^ ((row & 1) << 6) ^ (((row >> 1) & 3) << 4));
}
// GTS swizzle: pitch 768, XOR spreads column accesses across all banks
__device__ __forceinline__ int gts(int c, int bs) {   // bs = 2*s
    return GTSOF + c * 768 + (bs ^ ((c & 15) << 3));
}

__device__ __forceinline__ f32x4 mfma16(bf16x4 a, bf16x4 b, f32x4 c) {
#if __has_builtin(__builtin_amdgcn_mfma_f32_16x16x16bf16_1k)
    return __builtin_amdgcn_mfma_f32_16x16x16bf16_1k(a, b, c, 0, 0, 0);
#else
    asm volatile("v_mfma_f32_16x16x16_bf16 %0, %1, %2, %0"
                 : "+v"(c) : "v"(a), "v"(b));
    return c;
#endif
}

// ---------------------------------------------------------------------------
// One block per (b, m-half). 512 threads = 8 waves: wave = (sg 0..3, mg 0..1).
// K-loop: 12 chunks of K=64, double-buffered, ONE barrier per chunk; inside a
//   chunk two k-substeps share the barrier (ks=1 reads overlap ks=0 MFMAs).
//   Round-8 inner order: stage(next) -> loads(t+2) -> per-substep frag reads
//   interleaved with the 35-MFMA cluster.
// Then: GtS write, in-register masked softmax, PV with in-register P A-frags,
//   ordered cross-wave w2 reduce, square-sum, one atomic per (block, c).
// ---------------------------------------------------------------------------
__global__ __launch_bounds__(512, 2) void fused(const float* __restrict__ ctx,
                                                const float* __restrict__ resp,
                                                const float* __restrict__ pos,
                                                const int*  __restrict__ mask,
                                                float* __restrict__ out) {
    extern __shared__ char sm[];
    const int b   = blockIdx.x & 127;
    const int mh  = blockIdx.x >> 7;
    const int m0  = mh * MT;
    const int tid = threadIdx.x;
    const int ln  = tid & 63, wv = tid >> 6;
    const int l15 = ln & 15, g = ln >> 4;
    const int sg  = wv & 3, mg = wv >> 2;

    const float* __restrict__ ctxb  = ctx  + (size_t)b * nS * nH;
    const float* __restrict__ respb = resp + (size_t)b * nC * nH;

    // hoisted per-thread load offsets (elements); advance by k0 per chunk
    int cof[10], pof[5], rof[2];
    #pragma unroll
    for (int i = 0; i < 10; ++i) {
        int q = i * 512 + tid, r = q >> 4, kq = q & 15;
        int s = (r < nS) ? r : (nS - 1);
        cof[i] = s * nH + kq * 4;
    }
    #pragma unroll
    for (int i = 0; i < 5; ++i) {
        int q = i * 512 + tid, r = q >> 4, kq = q & 15;
        int m = m0 + r; if (m >= nM) m = nM - 1;
        pof[i] = m * nH + kq * 4;
    }
    #pragma unroll
    for (int i = 0; i < 2; ++i) {
        int q = i * 512 + tid, r = q >> 4, kq = q & 15;
        rof[i] = r * nH + kq * 4;
    }

    f32x4 acc[5][5];    // logits: D[s(sj)][m(mj)] swapped
    f32x4 gacc[5][2];   // G: D[s(sj)][c(cj within mg pair)]
    #pragma unroll
    for (int i = 0; i < 5; ++i) {
        #pragma unroll
        for (int j = 0; j < 5; ++j) acc[i][j] = (f32x4){0.f, 0.f, 0.f, 0.f};
        gacc[i][0] = (f32x4){0.f, 0.f, 0.f, 0.f};
        gacc[i][1] = (f32x4){0.f, 0.f, 0.f, 0.f};
    }

    float4 cR[10], pR[5], rR[2];
    auto loads = [&](int t) {
        const int k0 = t * KC;
        #pragma unroll
        for (int i = 0; i < 10; ++i) cR[i] = *(const float4*)(ctxb + cof[i] + k0);
        #pragma unroll
        for (int i = 0; i < 5; ++i)  pR[i] = *(const float4*)(pos + pof[i] + k0);
        #pragma unroll
        for (int i = 0; i < 2; ++i)  rR[i] = *(const float4*)(respb + rof[i] + k0);
    };
    auto stage = [&](char* base) {
        #pragma unroll
        for (int i = 0; i < 10; ++i) {
            int q = i * 512 + tid, r = q >> 4, kq = q & 15;
            *(uint2*)(base + STG_CTX + swz(r, kq * 8)) = cvt4(cR[i]);
        }
        #pragma unroll
        for (int i = 0; i < 5; ++i) {
            int q = i * 512 + tid, r = q >> 4, kq = q & 15;
            *(uint2*)(base + STG_POS + swz(r, kq * 8)) = cvt4(pR[i]);
        }
        #pragma unroll
        for (int i = 0; i < 2; ++i) {
            int q = i * 512 + tid, r = q >> 4, kq = q & 15;
            *(uint2*)(base + STG_RESP + swz(r, kq * 8)) = cvt4(rR[i]);
        }
    };

    // prologue: fill buf0 (chunk 0), load chunk 1 into regs
    loads(0);
    stage(sm);
    loads(1);
    __syncthreads();

    int cur = 0;
    for (int t = 0; t < NKC; ++t) {
        char* rbase = sm + cur * BUFSZ;
        if (t + 1 < NKC) stage(sm + (cur ^ 1) * BUFSZ);  // write next chunk
        if (t + 2 < NKC) loads(t + 2);                   // prefetch t+2
        #pragma unroll
        for (int ks = 0; ks < 2; ++ks) {
            const int kb = ks * 64 + g * 16;
            bf16x8 fp[5], fr[2];
            #pragma unroll
            for (int mj = 0; mj < 5; ++mj) {
                int r = 80 * mg + 16 * mj + l15;
                fp[mj] = *(const bf16x8*)(rbase + STG_POS + swz(r, kb));
            }
            #pragma unroll
            for (int cj = 0; cj < 2; ++cj) {
                int r = 16 * (2 * mg + cj) + l15;
                fr[cj] = *(const bf16x8*)(rbase + STG_RESP + swz(r, kb));
            }
            #pragma unroll
            for (int sj = 0; sj < 5; ++sj) {
                int r = 80 * sg + 16 * sj + l15;
                bf16x8 fa = *(const bf16x8*)(rbase + STG_CTX + swz(r, kb));
                #pragma unroll
                for (int mj = 0; mj < 5; ++mj)
                    acc[sj][mj] = __builtin_amdgcn_mfma_f32_16x16x32_bf16(fa, fp[mj], acc[sj][mj], 0, 0, 0);
                #pragma unroll
                for (int cj = 0; cj < 2; ++cj)
                    gacc[sj][cj] = __builtin_amdgcn_mfma_f32_16x16x32_bf16(fa, fr[cj], gacc[sj][cj], 0, 0, 0);
            }
        }
        __syncthreads();   // reads of buf[cur] done; writes of buf[cur^1] visible
        cur ^= 1;
    }

    // ---- GtS[c][s] bf16 (staging dead; overlays buffers) ----
    #pragma unroll
    for (int sj = 0; sj < 5; ++sj)
        #pragma unroll
        for (int cj = 0; cj < 2; ++cj) {
            int c = 16 * (2 * mg + cj) + l15;
            int s = 80 * sg + 16 * sj + 4 * g;
            *(uint2*)(sm + gts(c, 2 * s)) =
                make_uint2(pack2(gacc[sj][cj][0], gacc[sj][cj][1]),
                           pack2(gacc[sj][cj][2], gacc[sj][cj][3]));
        }

    // ---- multiplicative mask; pad s rows -> -inf ----
    #pragma unroll
    for (int sj = 0; sj < 5; ++sj)
        #pragma unroll
        for (int r = 0; r < 4; ++r) {
            int s = 80 * sg + 16 * sj + 4 * g + r;
            if (s < nS) {
                float mv = (float)mask[b * nS + s];
                #pragma unroll
                for (int mj = 0; mj < 5; ++mj) acc[sj][mj][r] *= mv;
            } else {
                #pragma unroll
                for (int mj = 0; mj < 5; ++mj) acc[sj][mj][r] = -1e30f;
            }
        }

    // ---- softmax over s: in-reg 20-reduce + shfl + LDS across 4 s-waves ----
    float* red1 = (float*)(sm + RED1);
    float* red2 = (float*)(sm + RED2);
    float inv[5];
    {
        float mx[5];
        #pragma unroll
        for (int mj = 0; mj < 5; ++mj) {
            float m = -1e30f;
            #pragma unroll
            for (int sj = 0; sj < 5; ++sj)
                #pragma unroll
                for (int r = 0; r < 4; ++r) m = fmaxf(m, acc[sj][mj][r]);
            m = fmaxf(m, __shfl_xor(m, 16));
            m = fmaxf(m, __shfl_xor(m, 32));
            mx[mj] = m;
        }
        if (ln < 16) {
            #pragma unroll
            for (int mj = 0; mj < 5; ++mj) red1[sg * 160 + 80 * mg + 16 * mj + ln] = mx[mj];
        }
        __syncthreads();   // also publishes GtS writes for PV
        float m4[5];
        #pragma unroll
        for (int mj = 0; mj < 5; ++mj) {
            int idx = 80 * mg + 16 * mj + l15;
            m4[mj] = fmaxf(fmaxf(red1[idx], red1[160 + idx]),
                           fmaxf(red1[320 + idx], red1[480 + idx]));
        }
        float sum[5];
        #pragma unroll
        for (int mj = 0; mj < 5; ++mj) {
            float s = 0.f;
            #pragma unroll
            for (int sj = 0; sj < 5; ++sj)
                #pragma unroll
                for (int r = 0; r < 4; ++r) {
                    float e = __expf(acc[sj][mj][r] - m4[mj]);
                    acc[sj][mj][r] = e;
                    s += e;
                }
            s += __shfl_xor(s, 16);
            s += __shfl_xor(s, 32);
            sum[mj] = s;
        }
        if (ln < 16) {
            #pragma unroll
            for (int mj = 0; mj < 5; ++mj) red2[sg * 160 + 80 * mg + 16 * mj + ln] = sum[mj];
        }
        __syncthreads();
        #pragma unroll
        for (int mj = 0; mj < 5; ++mj) {
            int idx = 80 * mg + 16 * mj + l15;
            float tt = red2[idx] + red2[160 + idx] + red2[320 + idx] + red2[480 + idx];
            int mglob = m0 + 80 * mg + 16 * mj + l15;
            inv[mj] = (mglob < nM) ? (1.0f / tt) : 0.0f;   // pad m rows -> P = 0
        }
    }

    // ---- P in-register (16x16x16 A-layout: k = 4*g + j matches swapped C) ----
    union PU { uint2 u; bf16x4 v; };
    bf16x4 P[5][5];
    #pragma unroll
    for (int sj = 0; sj < 5; ++sj)
        #pragma unroll
        for (int mj = 0; mj < 5; ++mj) {
            PU pu;
            pu.u = make_uint2(pack2(acc[sj][mj][0] * inv[mj], acc[sj][mj][1] * inv[mj]),
                              pack2(acc[sj][mj][2] * inv[mj], acc[sj][mj][3] * inv[mj]));
            P[sj][mj] = pu.v;
        }

    // ---- PV: partial w2 over this wave's s-range ----
    f32x4 pacc[5][4];
    #pragma unroll
    for (int mj = 0; mj < 5; ++mj)
        #pragma unroll
        for (int cj = 0; cj < 4; ++cj) pacc[mj][cj] = (f32x4){0.f, 0.f, 0.f, 0.f};
    #pragma unroll
    for (int sj = 0; sj < 5; ++sj) {
        int s = 80 * sg + 16 * sj + 4 * g;
        #pragma unroll
        for (int cj = 0; cj < 4; ++cj) {
            int c = 16 * cj + l15;
            bf16x4 B = *(const bf16x4*)(sm + gts(c, 2 * s));
            #pragma unroll
            for (int mj = 0; mj < 5; ++mj) pacc[mj][cj] = mfma16(P[sj][mj], B, pacc[mj][cj]);
        }
    }
    __syncthreads();   // all GTS reads done -> w2r may overlay

    // ---- ordered cross-wave w2 reduce, float4, layout w2r[c][172] ----
    float* w2r = (float*)(sm + W2R);
    for (int pass = 0; pass < 4; ++pass) {
        if (sg == pass) {
            #pragma unroll
            for (int cj = 0; cj < 4; ++cj) {
                int c = 16 * cj + l15;
                #pragma unroll
                for (int mj = 0; mj < 5; ++mj) {
                    int m = 80 * mg + 16 * mj + 4 * g;
                    float* p = w2r + c * 172 + m;
                    f32x4 v = pacc[mj][cj];
                    if (pass == 0) {
                        *(f32x4*)p = v;
                    } else {
                        f32x4 o = *(const f32x4*)p;
                        o[0] += v[0]; o[1] += v[1]; o[2] += v[2]; o[3] += v[3];
                        *(f32x4*)p = o;
                    }
                }
            }
        }
        __syncthreads();
    }

    // ---- dot partial = sum_m w2^2 ; one atomic per (block, c) ----
    float* fred = (float*)(sm + RED1);
    {
        int c = tid & 63, g8 = wv;          // wave g8 handles m in [20*g8, 20*g8+20)
        float s = 0.f;
        #pragma unroll
        for (int j = 0; j < 5; ++j) {
            f32x4 v = *(const f32x4*)(w2r + c * 172 + 20 * g8 + 4 * j);
            s += v[0] * v[0] + v[1] * v[1] + v[2] * v[2] + v[3] * v[3];
        }
        fred[g8 * 64 + c] = s;
    }
    __syncthreads();
    if (tid < 64) {
        float t = 0.f;
        #pragma unroll
        for (int j = 0; j < 8; ++j) t += fred[j * 64 + tid];
        atomicAdd(out + b * nC + tid, t);
    }
}

extern "C" void kernel_launch(void* const* d_in, const int* in_sizes, int n_in,
                              void* d_out, int out_size, void* d_ws, size_t ws_size,
                              hipStream_t stream) {
    const float* ctx  = (const float*)d_in[0];   // [B,S,H]
    const float* resp = (const float*)d_in[1];   // [B,C,H]
    const float* pos  = (const float*)d_in[2];   // [M,H]
    const int*   mask = (const int*)d_in[3];     // [B,S]
    float* out = (float*)d_out;                  // [B,C]

    (void)hipFuncSetAttribute((const void*)fused,
                              hipFuncAttributeMaxDynamicSharedMemorySize, LDSB);
    (void)hipMemsetAsync(d_out, 0, (size_t)nB * nC * sizeof(float), stream);
    fused<<<nB * 2, 512, LDSB, stream>>>(ctx, resp, pos, mask, out);
}

// Round 11
// 51.239 us; speedup vs baseline: 1.9173x; 1.9173x over previous
//
#include <hip/hip_runtime.h>
#include <hip/hip_bf16.h>

using bf16x8 = __attribute__((ext_vector_type(8))) short;
using bf16x4 = __attribute__((ext_vector_type(4))) short;
using f32x4  = __attribute__((ext_vector_type(4))) float;

namespace {
constexpr int nB = 128, nS = 300, nC = 64, nH = 768, nM = 300;
constexpr int MT  = 160;            // m-tile per block (2 blocks per b)
constexpr int KC  = 32;             // k chunk
constexpr int NKC = nH / KC;        // 24
// LDS (bytes). K-loop: two staging buffers [0, 69632).
// Post-K-loop overlays (staging dead): GTS [0,49152); after PV: W2R [0,44032).
// RED1/RED2 sit in buf1's tail (dead post-K-loop).
constexpr int BUFSZ    = 34816;     // ctx 20480 + pos 10240 + resp 4096
constexpr int STG_CTX  = 0;         // [320 s][64 B] bf16 chunk, XOR-swizzled
constexpr int STG_POS  = 20480;     // [160 m][64 B]
constexpr int STG_RESP = 30720;     // [64 c][64 B]
constexpr int GTSOF    = 0;         // [64 c][768 B] bf16, XOR (c&15)<<3
constexpr int W2R      = 0;         // [64 c][172 f32] (post-PV only)
constexpr int RED1     = 49152;     // 2560 B (softmax max / final fred)
constexpr int RED2     = 51712;     // 2560 B (softmax sum)
constexpr int LDSB     = 69632;
}

// fp32 -> packed 2x bf16 RNE via the HIP intrinsic (expected to lower to
// v_cvt_pk_bf16_f32; round-6's hand-rolled asm NaN'd -- header impl is safe
// and RNE-identical either way). memcpy extraction avoids the
// not-trivially-copyable bit_cast error from round 4.
__device__ __forceinline__ unsigned pack2(float a, float b) {
    float2 f2; f2.x = a; f2.y = b;
    __hip_bfloat162 h2 = __float22bfloat162_rn(f2);
    unsigned u;
    __builtin_memcpy(&u, &h2, 4);
    return u;
}
__device__ __forceinline__ uint2 cvt4(float4 v) {
    return make_uint2(pack2(v.x, v.y), pack2(v.z, v.w));
}
// staging swizzle (64B rows): slot XOR uses (r>>1)&3 so over 8 consecutive
// rows the bank-quad (4r + slot) mod 8 hits all 8 quads -> 16-lane frag reads
// land 2 lanes/quad = conflict-free (verified round 8: 2.56M -> 205K).
__device__ __forceinline__ int swz(int row, int bcol) {
    return row * 64 + (bcol ^ (((row >> 1) & 3) << 4));
}
// GTS swizzle: pitch 768, XOR spreads the 16 8B-slots of a column access
// across all 32 banks (balanced for both write and PV read)
__device__ __forceinline__ int gts(int c, int bs) {   // bs = 2*s
    return GTSOF + c * 768 + (bs ^ ((c & 15) << 3));
}

__device__ __forceinline__ f32x4 mfma16(bf16x4 a, bf16x4 b, f32x4 c) {
#if __has_builtin(__builtin_amdgcn_mfma_f32_16x16x16bf16_1k)
    return __builtin_amdgcn_mfma_f32_16x16x16bf16_1k(a, b, c, 0, 0, 0);
#else
    asm volatile("v_mfma_f32_16x16x16_bf16 %0, %1, %2, %0"
                 : "+v"(c) : "v"(a), "v"(b));
    return c;
#endif
}

// ---------------------------------------------------------------------------
// One block per (b, m-half). 512 threads = 8 waves: wave = (sg 0..3, mg 0..1).
// K-loop (round-8 schedule, proven): stage(next) -> loads(t+2) -> per-sj frag
//   reads interleaved with the 35-MFMA cluster; ONE barrier per chunk.
// Then: GtS write, in-register masked softmax, PV with in-register P A-frags,
//   ordered cross-wave w2 reduce, square-sum, one atomic per (block, c).
// ---------------------------------------------------------------------------
__global__ __launch_bounds__(512, 2) void fused(const float* __restrict__ ctx,
                                                const float* __restrict__ resp,
                                                const float* __restrict__ pos,
                                                const int*  __restrict__ mask,
                                                float* __restrict__ out) {
    extern __shared__ char sm[];
    const int b   = blockIdx.x & 127;
    const int mh  = blockIdx.x >> 7;
    const int m0  = mh * MT;
    const int tid = threadIdx.x;
    const int ln  = tid & 63, wv = tid >> 6;
    const int l15 = ln & 15, g = ln >> 4;
    const int sg  = wv & 3, mg = wv >> 2;

    const float* __restrict__ ctxb  = ctx  + (size_t)b * nS * nH;
    const float* __restrict__ respb = resp + (size_t)b * nC * nH;

    // hoisted per-thread load pointers (advance by k0 only)
    const float* pcx[5];
    #pragma unroll
    for (int i = 0; i < 5; ++i) {
        int q = i * 512 + tid, r = q >> 3, kq = q & 7;
        int s = (r < nS) ? r : (nS - 1);
        pcx[i] = ctxb + (size_t)s * nH + kq * 4;
    }
    const float* ppx[3];
    #pragma unroll
    for (int i = 0; i < 3; ++i) {
        int q = i * 512 + tid, r = q >> 3, kq = q & 7;
        int m = m0 + r; if (m >= nM) m = nM - 1;
        ppx[i] = pos + (size_t)m * nH + kq * 4;
    }
    const float* prx = respb + (size_t)(tid >> 3) * nH + (tid & 7) * 4;

    f32x4 acc[5][5];    // logits: D[s(sj)][m(mj)] swapped
    f32x4 gacc[5][2];   // G: D[s(sj)][c(cj within mg pair)]
    #pragma unroll
    for (int i = 0; i < 5; ++i) {
        #pragma unroll
        for (int j = 0; j < 5; ++j) acc[i][j] = (f32x4){0.f, 0.f, 0.f, 0.f};
        gacc[i][0] = (f32x4){0.f, 0.f, 0.f, 0.f};
        gacc[i][1] = (f32x4){0.f, 0.f, 0.f, 0.f};
    }

    float4 cR[5], pR[3], rR;
    auto loads = [&](int t) {
        const int k0 = t * KC;
        #pragma unroll
        for (int i = 0; i < 5; ++i) cR[i] = *(const float4*)(pcx[i] + k0);
        #pragma unroll
        for (int i = 0; i < 3; ++i)
            if (i * 512 + tid < 1280) pR[i] = *(const float4*)(ppx[i] + k0);
        rR = *(const float4*)(prx + k0);
    };
    auto stage = [&](char* base) {
        #pragma unroll
        for (int i = 0; i < 5; ++i) {
            int q = i * 512 + tid, r = q >> 3, kq = q & 7;
            *(uint2*)(base + STG_CTX + swz(r, kq * 8)) = cvt4(cR[i]);
        }
        #pragma unroll
        for (int i = 0; i < 3; ++i) {
            int q = i * 512 + tid;
            if (q < 1280) {
                int r = q >> 3, kq = q & 7;
                *(uint2*)(base + STG_POS + swz(r, kq * 8)) = cvt4(pR[i]);
            }
        }
        { int r = tid >> 3, kq = tid & 7;
          *(uint2*)(base + STG_RESP + swz(r, kq * 8)) = cvt4(rR); }
    };

    // prologue: fill buf0 (chunk 0), load chunk 1 into regs
    loads(0);
    stage(sm);
    loads(1);
    __syncthreads();

    int cur = 0;
    for (int t = 0; t < NKC; ++t) {
        char* rbase = sm + cur * BUFSZ;
        if (t + 1 < NKC) stage(sm + (cur ^ 1) * BUFSZ);  // write next chunk
        if (t + 2 < NKC) loads(t + 2);                   // prefetch t+2
        bf16x8 fp[5], fr[2];
        #pragma unroll
        for (int mj = 0; mj < 5; ++mj) {
            int r = 80 * mg + 16 * mj + l15;
            fp[mj] = *(const bf16x8*)(rbase + STG_POS + swz(r, g * 16));
        }
        #pragma unroll
        for (int cj = 0; cj < 2; ++cj) {
            int r = 16 * (2 * mg + cj) + l15;
            fr[cj] = *(const bf16x8*)(rbase + STG_RESP + swz(r, g * 16));
        }
        #pragma unroll
        for (int sj = 0; sj < 5; ++sj) {
            int r = 80 * sg + 16 * sj + l15;
            bf16x8 fa = *(const bf16x8*)(rbase + STG_CTX + swz(r, g * 16));
            #pragma unroll
            for (int mj = 0; mj < 5; ++mj)
                acc[sj][mj] = __builtin_amdgcn_mfma_f32_16x16x32_bf16(fa, fp[mj], acc[sj][mj], 0, 0, 0);
            #pragma unroll
            for (int cj = 0; cj < 2; ++cj)
                gacc[sj][cj] = __builtin_amdgcn_mfma_f32_16x16x32_bf16(fa, fr[cj], gacc[sj][cj], 0, 0, 0);
        }
        __syncthreads();   // reads of buf[cur] done; writes of buf[cur^1] visible
        cur ^= 1;
    }

    // ---- GtS[c][s] bf16 (staging dead; overlays buffers) ----
    #pragma unroll
    for (int sj = 0; sj < 5; ++sj)
        #pragma unroll
        for (int cj = 0; cj < 2; ++cj) {
            int c = 16 * (2 * mg + cj) + l15;
            int s = 80 * sg + 16 * sj + 4 * g;
            *(uint2*)(sm + gts(c, 2 * s)) =
                make_uint2(pack2(gacc[sj][cj][0], gacc[sj][cj][1]),
                           pack2(gacc[sj][cj][2], gacc[sj][cj][3]));
        }

    // ---- multiplicative mask; pad s rows -> -inf ----
    #pragma unroll
    for (int sj = 0; sj < 5; ++sj)
        #pragma unroll
        for (int r = 0; r < 4; ++r) {
            int s = 80 * sg + 16 * sj + 4 * g + r;
            if (s < nS) {
                float mv = (float)mask[b * nS + s];
                #pragma unroll
                for (int mj = 0; mj < 5; ++mj) acc[sj][mj][r] *= mv;
            } else {
                #pragma unroll
                for (int mj = 0; mj < 5; ++mj) acc[sj][mj][r] = -1e30f;
            }
        }

    // ---- softmax over s: in-reg 20-reduce + shfl + LDS across 4 s-waves ----
    float* red1 = (float*)(sm + RED1);
    float* red2 = (float*)(sm + RED2);
    float inv[5];
    {
        float mx[5];
        #pragma unroll
        for (int mj = 0; mj < 5; ++mj) {
            float m = -1e30f;
            #pragma unroll
            for (int sj = 0; sj < 5; ++sj)
                #pragma unroll
                for (int r = 0; r < 4; ++r) m = fmaxf(m, acc[sj][mj][r]);
            m = fmaxf(m, __shfl_xor(m, 16));
            m = fmaxf(m, __shfl_xor(m, 32));
            mx[mj] = m;
        }
        if (ln < 16) {
            #pragma unroll
            for (int mj = 0; mj < 5; ++mj) red1[sg * 160 + 80 * mg + 16 * mj + ln] = mx[mj];
        }
        __syncthreads();   // also publishes GtS writes for PV
        float m4[5];
        #pragma unroll
        for (int mj = 0; mj < 5; ++mj) {
            int idx = 80 * mg + 16 * mj + l15;
            m4[mj] = fmaxf(fmaxf(red1[idx], red1[160 + idx]),
                           fmaxf(red1[320 + idx], red1[480 + idx]));
        }
        float sum[5];
        #pragma unroll
        for (int mj = 0; mj < 5; ++mj) {
            float s = 0.f;
            #pragma unroll
            for (int sj = 0; sj < 5; ++sj)
                #pragma unroll
                for (int r = 0; r < 4; ++r) {
                    float e = __expf(acc[sj][mj][r] - m4[mj]);
                    acc[sj][mj][r] = e;
                    s += e;
                }
            s += __shfl_xor(s, 16);
            s += __shfl_xor(s, 32);
            sum[mj] = s;
        }
        if (ln < 16) {
            #pragma unroll
            for (int mj = 0; mj < 5; ++mj) red2[sg * 160 + 80 * mg + 16 * mj + ln] = sum[mj];
        }
        __syncthreads();
        #pragma unroll
        for (int mj = 0; mj < 5; ++mj) {
            int idx = 80 * mg + 16 * mj + l15;
            float tt = red2[idx] + red2[160 + idx] + red2[320 + idx] + red2[480 + idx];
            int mglob = m0 + 80 * mg + 16 * mj + l15;
            inv[mj] = (mglob < nM) ? (1.0f / tt) : 0.0f;   // pad m rows -> P = 0
        }
    }

    // ---- P in-register (16x16x16 A-layout: k = 4*g + j matches swapped C) ----
    union PU { uint2 u; bf16x4 v; };
    bf16x4 P[5][5];
    #pragma unroll
    for (int sj = 0; sj < 5; ++sj)
        #pragma unroll
        for (int mj = 0; mj < 5; ++mj) {
            PU pu;
            pu.u = make_uint2(pack2(acc[sj][mj][0] * inv[mj], acc[sj][mj][1] * inv[mj]),
                              pack2(acc[sj][mj][2] * inv[mj], acc[sj][mj][3] * inv[mj]));
            P[sj][mj] = pu.v;
        }

    // ---- PV: partial w2 over this wave's s-range ----
    f32x4 pacc[5][4];
    #pragma unroll
    for (int mj = 0; mj < 5; ++mj)
        #pragma unroll
        for (int cj = 0; cj < 4; ++cj) pacc[mj][cj] = (f32x4){0.f, 0.f, 0.f, 0.f};
    #pragma unroll
    for (int sj = 0; sj < 5; ++sj) {
        int s = 80 * sg + 16 * sj + 4 * g;
        #pragma unroll
        for (int cj = 0; cj < 4; ++cj) {
            int c = 16 * cj + l15;
            bf16x4 B = *(const bf16x4*)(sm + gts(c, 2 * s));
            #pragma unroll
            for (int mj = 0; mj < 5; ++mj) pacc[mj][cj] = mfma16(P[sj][mj], B, pacc[mj][cj]);
        }
    }
    __syncthreads();   // all GTS reads done -> w2r may overlay

    // ---- ordered cross-wave w2 reduce, float4, layout w2r[c][172] ----
    float* w2r = (float*)(sm + W2R);
    for (int pass = 0; pass < 4; ++pass) {
        if (sg == pass) {
            #pragma unroll
            for (int cj = 0; cj < 4; ++cj) {
                int c = 16 * cj + l15;
                #pragma unroll
                for (int mj = 0; mj < 5; ++mj) {
                    int m = 80 * mg + 16 * mj + 4 * g;
                    float* p = w2r + c * 172 + m;
                    f32x4 v = pacc[mj][cj];
                    if (pass == 0) {
                        *(f32x4*)p = v;
                    } else {
                        f32x4 o = *(const f32x4*)p;
                        o[0] += v[0]; o[1] += v[1]; o[2] += v[2]; o[3] += v[3];
                        *(f32x4*)p = o;
                    }
                }
            }
        }
        __syncthreads();
    }

    // ---- dot partial = sum_m w2^2 ; one atomic per (block, c) ----
    float* fred = (float*)(sm + RED1);
    {
        int c = tid & 63, g8 = wv;          // wave g8 handles m in [20*g8, 20*g8+20)
        float s = 0.f;
        #pragma unroll
        for (int j = 0; j < 5; ++j) {
            f32x4 v = *(const f32x4*)(w2r + c * 172 + 20 * g8 + 4 * j);
            s += v[0] * v[0] + v[1] * v[1] + v[2] * v[2] + v[3] * v[3];
        }
        fred[g8 * 64 + c] = s;
    }
    __syncthreads();
    if (tid < 64) {
        float t = 0.f;
        #pragma unroll
        for (int j = 0; j < 8; ++j) t += fred[j * 64 + tid];
        atomicAdd(out + b * nC + tid, t);
    }
}

extern "C" void kernel_launch(void* const* d_in, const int* in_sizes, int n_in,
                              void* d_out, int out_size, void* d_ws, size_t ws_size,
                              hipStream_t stream) {
    const float* ctx  = (const float*)d_in[0];   // [B,S,H]
    const float* resp = (const float*)d_in[1];   // [B,C,H]
    const float* pos  = (const float*)d_in[2];   // [M,H]
    const int*   mask = (const int*)d_in[3];     // [B,S]
    float* out = (float*)d_out;                  // [B,C]

    (void)hipFuncSetAttribute((const void*)fused,
                              hipFuncAttributeMaxDynamicSharedMemorySize, LDSB);
    (void)hipMemsetAsync(d_out, 0, (size_t)nB * nC * sizeof(float), stream);
    fused<<<nB * 2, 512, LDSB, stream>>>(ctx, resp, pos, mask, out);
}